// Round 5
// baseline (238.347 us; speedup 1.0000x reference)
//
#include <hip/hip_runtime.h>

typedef unsigned short u16;
typedef unsigned int   u32;
typedef __bf16 bf16x8 __attribute__((ext_vector_type(8)));
typedef float  f32x4  __attribute__((ext_vector_type(4)));

union U16B { int4 i4; bf16x8 b8; u16 u[8]; };
union U16Q { uint2 d2; u16 u[4]; };
union PK4  { uint2 d2; __bf16 b[4]; };

static __device__ __forceinline__ u16 f2b(float f) {
  u32 x = __float_as_uint(f);
  x += 0x7FFFu + ((x >> 16) & 1u);   // RNE (inputs finite)
  return (u16)(x >> 16);
}
static __device__ __forceinline__ float b2f(u16 s) {
  return __uint_as_float(((u32)s) << 16);
}

// ---------------- fp32 -> bf16 convert (inputs, once) ----------------
struct ConvA { const float* src[3]; u16* dst[3]; };

__global__ __launch_bounds__(256) void convA(ConvA a) {
  const float* s = a.src[blockIdx.z];
  u16*         d = a.dst[blockIdx.z];
  const size_t i = ((size_t)blockIdx.x * 256 + threadIdx.x) * 8;
  float4 f0 = *(const float4*)(s + i);
  float4 f1 = *(const float4*)(s + i + 4);
  U16B t;
  t.u[0] = f2b(f0.x); t.u[1] = f2b(f0.y); t.u[2] = f2b(f0.z); t.u[3] = f2b(f0.w);
  t.u[4] = f2b(f1.x); t.u[5] = f2b(f1.y); t.u[6] = f2b(f1.z); t.u[7] = f2b(f1.w);
  *(int4*)(d + i) = t.i4;
}

// ---------------- weight transpose + fp32->bf16 convert ----------------
struct TransA { const float* W[4]; u16* Wt[4]; };

__global__ __launch_bounds__(256) void transW(TransA a) {
  const float* W  = a.W[blockIdx.z];
  u16*         Wt = a.Wt[blockIdx.z];
  __shared__ float t[64][65];
  const int bx = blockIdx.x * 64, by = blockIdx.y * 64;
  const int tx = threadIdx.x & 63, ty = threadIdx.x >> 6;
  #pragma unroll
  for (int j = 0; j < 16; ++j) {
    int row = j * 4 + ty;
    t[row][tx] = W[(size_t)(by + row) * 1024 + bx + tx];
  }
  __syncthreads();
  #pragma unroll
  for (int j = 0; j < 16; ++j) {
    int row = j * 4 + ty;           // Wt[n][k] = W[k][n]
    Wt[(size_t)(bx + row) * 1024 + by + tx] = f2b(t[tx][row]);
  }
}

// ---------------- GEMM: C = A[M][K](bf16) * Bt[N][K]^T + bias ----------------
// 128x128 tile, BK=64, 4 waves, XOR-swizzled LDS. Flat grid with XCD swizzle:
// logical = (bid%8)*cpx + bid/8; 256 logical blocks per z (8 x * 32 y).
// mode: 0=bf16 row-major, 1=f32 row-major, 2=bf16 transposed C^T[N][4096].
struct GemmB { const u16* A[3]; const u16* Bt[3]; const float* bias[3]; void* C[3]; int mode[3]; int cpx; };

__global__ __launch_bounds__(256) void gemm_bt(GemmB g) {
  constexpr int K = 1024, N = 1024;
  __shared__ u16 As[128 * 64];
  __shared__ u16 Bs[128 * 64];
  const int bid = blockIdx.x;
  const int lg = (bid & 7) * g.cpx + (bid >> 3);
  const int z = lg >> 8;
  const int rem = lg & 255;
  const int row0 = (rem >> 3) * 128, col0 = (rem & 7) * 128;
  const u16*   Ap   = g.A[z];
  const u16*   Bt   = g.Bt[z];
  const float* bias = g.bias[z];
  const int mode = g.mode[z];
  const int tid = threadIdx.x;
  const int wid = tid >> 6, lane = tid & 63;
  const int wr = wid >> 1, wc = wid & 1;
  const int lo = lane & 15, hi = lane >> 4;
  const int rs = tid >> 3, us = tid & 7;

  f32x4 acc[4][4];
  const f32x4 z4 = {0.f, 0.f, 0.f, 0.f};
  #pragma unroll
  for (int i = 0; i < 4; ++i)
    #pragma unroll
    for (int j = 0; j < 4; ++j) acc[i][j] = z4;

  for (int kt = 0; kt < K / 64; ++kt) {
    __syncthreads();
    #pragma unroll
    for (int c = 0; c < 4; ++c) {
      int r = c * 32 + rs;
      int lds = r * 64 + ((us ^ (r & 7)) << 3);
      *(int4*)&As[lds] = *(const int4*)(Ap + (size_t)(row0 + r) * K + kt * 64 + us * 8);
      *(int4*)&Bs[lds] = *(const int4*)(Bt + (size_t)(col0 + r) * K + kt * 64 + us * 8);
    }
    __syncthreads();
    #pragma unroll
    for (int ks = 0; ks < 2; ++ks) {
      bf16x8 af[4], bfr[4];
      #pragma unroll
      for (int mf = 0; mf < 4; ++mf) {
        int r = wr * 64 + mf * 16 + lo;
        af[mf] = *(const bf16x8*)&As[r * 64 + (((ks * 4 + hi) ^ (r & 7)) << 3)];
      }
      #pragma unroll
      for (int nf = 0; nf < 4; ++nf) {
        int r = wc * 64 + nf * 16 + lo;
        bfr[nf] = *(const bf16x8*)&Bs[r * 64 + (((ks * 4 + hi) ^ (r & 7)) << 3)];
      }
      #pragma unroll
      for (int mf = 0; mf < 4; ++mf)
        #pragma unroll
        for (int nf = 0; nf < 4; ++nf)
          acc[mf][nf] = __builtin_amdgcn_mfma_f32_16x16x32_bf16(af[mf], bfr[nf], acc[mf][nf], 0, 0, 0);
    }
  }

  #pragma unroll
  for (int nf = 0; nf < 4; ++nf) {
    int col = col0 + wc * 64 + nf * 16 + lo;
    float bv = bias[col];
    #pragma unroll
    for (int mf = 0; mf < 4; ++mf) {
      int rb = row0 + wr * 64 + mf * 16 + hi * 4;   // C/D: row=(l>>4)*4+e, col=l&15
      if (mode == 2) {
        U16Q q4;
        #pragma unroll
        for (int e = 0; e < 4; ++e) q4.u[e] = f2b(acc[mf][nf][e] + bv);
        *(uint2*)&((u16*)g.C[z])[(size_t)col * 4096 + rb] = q4.d2;   // C^T[N][4096]
      } else {
        #pragma unroll
        for (int e = 0; e < 4; ++e) {
          float v = acc[mf][nf][e] + bv;
          if (mode == 1) ((float*)g.C[z])[(size_t)(rb + e) * N + col] = v;
          else           ((u16*)g.C[z])[(size_t)(rb + e) * N + col] = f2b(v);
        }
      }
    }
  }
}

// ---------------- flash attention ----------------
// ROUND-3 STRUCTURE (known-good 84.5us): 64 q-rows/block, 4 waves x 16 rows,
// KBLK=64, single-buffered tiles, TWO barriers per k-iter. Changes vs R3:
//  (1) P-pack via native __bf16 casts (v_cvt_pk_bf16_f32), not bit-twiddle f2b
//  (2) defer-max THR=8: O-rescale only when tile max grows (log2 domain)
//  (3) staging loads issued BEFORE the first barrier (latency under barrier)
// R4's single-barrier/dbuf/prefetch bundle added ~70us stall - reverted.
__global__ __launch_bounds__(256) void attn_fwd(const u16* __restrict__ Q,
                                                const u16* __restrict__ Kp,
                                                const u16* __restrict__ VpT,
                                                u16* __restrict__ O) {
  __shared__ u16 Ks[64 * 64];    // K tile [kk][d], XOR-swizzled rows
  __shared__ u16 Vts[64 * 64];   // V^T tile [d][kk], XOR-swizzled rows
  __shared__ u16 Ps[64 * 64];    // P tile [q][kk], per-wave rows, swizzled
  const int tid = threadIdx.x;
  const int bid = blockIdx.x;    // XCD decode: xcd=bid&7 owns 4 (h,b) pairs
  const int t = bid >> 3;
  const int hb = (bid & 7) * 4 + (t >> 5);
  const int qb = t & 31;
  const int h = hb & 15, b = hb >> 4;
  const int wid = tid >> 6, lane = tid & 63;
  const int lo = lane & 15, hi = lane >> 4;
  const int rs = tid >> 3, us = tid & 7;
  const int hoff = h * 64;
  const size_t rowQ0 = (size_t)b * 2048 + (size_t)qb * 64;
  const float QSCALE = 0.125f * 1.4426950408889634f;

  const u16* kBase = Kp + ((size_t)b * 2048) * 1024 + hoff + us * 8;        // + (kv0+r)*1024
  const u16* vBase = VpT + (size_t)hoff * 4096 + (size_t)b * 2048 + us * 8; // + r*4096 + kv0

  // Q fragments (B-operand): lane holds Q[q=wid*16+lo][d=ks*32+hi*8..], pre-scaled
  bf16x8 qf[2];
  #pragma unroll
  for (int ks = 0; ks < 2; ++ks) {
    size_t r = rowQ0 + wid * 16 + lo;
    U16B in; in.i4 = *(const int4*)&Q[r * 1024 + hoff + ks * 32 + hi * 8];
    U16B o;
    #pragma unroll
    for (int j = 0; j < 8; ++j) o.u[j] = f2b(b2f(in.u[j]) * QSCALE);
    qf[ks] = o.b8;
  }

  f32x4 oacc[4];
  const f32x4 z4 = {0.f, 0.f, 0.f, 0.f};
  #pragma unroll
  for (int df = 0; df < 4; ++df) oacc[df] = z4;
  float m_r = -1e30f, l_r = 0.f;   // row stats for q=wid*16+lo (replicated over hi)

  for (int kb = 0; kb < 32; ++kb) {
    const int kv0 = kb * 64;
    // issue staging loads BEFORE the barrier: latency hides under barrier wait
    int4 gk[2], gv[2];
    #pragma unroll
    for (int c = 0; c < 2; ++c) {
      int r = c * 32 + rs;
      gk[c] = *(const int4*)(kBase + (size_t)(kv0 + r) * 1024);
      gv[c] = *(const int4*)(vBase + (size_t)r * 4096 + kv0);
    }
    __syncthreads();   // prev iter's tile reads done
    #pragma unroll
    for (int c = 0; c < 2; ++c) {
      int r = c * 32 + rs;
      int lds = r * 64 + ((us ^ (r & 7)) << 3);
      *(int4*)&Ks[lds]  = gk[c];
      *(int4*)&Vts[lds] = gv[c];
    }
    __syncthreads();   // tile visible

    // S^T = K Q^T : frag nf covers kk = nf*16+hi*4+e, q = wid*16+lo
    f32x4 sfr[4];
    #pragma unroll
    for (int nf = 0; nf < 4; ++nf) sfr[nf] = z4;
    #pragma unroll
    for (int ks = 0; ks < 2; ++ks) {
      #pragma unroll
      for (int nf = 0; nf < 4; ++nf) {
        int kk = nf * 16 + lo;
        bf16x8 kf = *(const bf16x8*)&Ks[kk * 64 + (((ks * 4 + hi) ^ (kk & 7)) << 3)];
        sfr[nf] = __builtin_amdgcn_mfma_f32_16x16x32_bf16(kf, qf[ks], sfr[nf], 0, 0, 0);
      }
    }

    // online softmax (16 scores/lane for q=wid*16+lo; 2-shfl row reduce)
    float pm = -1e30f;
    #pragma unroll
    for (int nf = 0; nf < 4; ++nf)
      #pragma unroll
      for (int e = 0; e < 4; ++e) pm = fmaxf(pm, sfr[nf][e]);
    pm = fmaxf(pm, __shfl_xor(pm, 16));
    pm = fmaxf(pm, __shfl_xor(pm, 32));
    if (!__all(pm <= m_r + 8.0f)) {   // defer-max: rescale only on real growth
      float mn = fmaxf(m_r, pm);
      float cc = __builtin_amdgcn_exp2f(m_r - mn);
      m_r = mn;
      l_r *= cc;
      float cce[4];
      #pragma unroll
      for (int e = 0; e < 4; ++e) cce[e] = __shfl(cc, hi * 4 + e);
      #pragma unroll
      for (int df = 0; df < 4; ++df)
        #pragma unroll
        for (int e = 0; e < 4; ++e) oacc[df][e] *= cce[e];
    }
    float ps = 0.f;
    #pragma unroll
    for (int nf = 0; nf < 4; ++nf) {
      PK4 pk;
      #pragma unroll
      for (int e = 0; e < 4; ++e) {
        float p = __builtin_amdgcn_exp2f(sfr[nf][e] - m_r);
        ps += p;
        pk.b[e] = (__bf16)p;     // native cast -> v_cvt_pk_bf16_f32
      }
      *(uint2*)&Ps[(wid * 16 + lo) * 64 + ((nf * 16 + hi * 4) ^ ((lo & 7) << 3))] = pk.d2;
    }
    ps += __shfl_xor(ps, 16);
    ps += __shfl_xor(ps, 32);
    l_r += ps;

    // O += P V  (P-write -> PV-read ordering within wave: compiler-inserted
    // lgkmcnt waits, as validated in round 3)
    #pragma unroll
    for (int ksp = 0; ksp < 2; ++ksp) {
      bf16x8 pa = *(const bf16x8*)&Ps[(wid * 16 + lo) * 64 + ((((ksp * 4 + hi) ^ (lo & 7))) << 3)];
      bf16x8 vb[4];
      #pragma unroll
      for (int df = 0; df < 4; ++df) {
        int d = df * 16 + lo;
        vb[df] = *(const bf16x8*)&Vts[d * 64 + (((ksp * 4 + hi) ^ (d & 7)) << 3)];
      }
      #pragma unroll
      for (int df = 0; df < 4; ++df)
        oacc[df] = __builtin_amdgcn_mfma_f32_16x16x32_bf16(pa, vb[df], oacc[df], 0, 0, 0);
    }
  }

  // epilogue: normalize (stats at q=wid*16+lo; O rows q=hi*4+e -> shfl gather)
  float inv = __builtin_amdgcn_rcpf(l_r);
  float inve[4];
  #pragma unroll
  for (int e = 0; e < 4; ++e) inve[e] = __shfl(inv, hi * 4 + e);
  #pragma unroll
  for (int df = 0; df < 4; ++df)
    #pragma unroll
    for (int e = 0; e < 4; ++e) {
      size_t row = rowQ0 + wid * 16 + hi * 4 + e;
      O[row * 1024 + hoff + df * 16 + lo] = f2b(oacc[df][e] * inve[e]);
    }
}

// ---------------- launch ----------------
extern "C" void kernel_launch(void* const* d_in, const int* in_sizes, int n_in,
                              void* d_out, int out_size, void* d_ws, size_t ws_size,
                              hipStream_t stream) {
  (void)in_sizes; (void)n_in; (void)out_size;
  const size_t MB = 1024 * 1024;
  if (ws_size < 40 * MB) return;
  char* ws = (char*)d_ws;
  u16* Wqt = (u16*)(ws + 0 * MB);
  u16* Wkt = (u16*)(ws + 2 * MB);
  u16* Wvt = (u16*)(ws + 4 * MB);
  u16* Wot = (u16*)(ws + 6 * MB);
  u16* Vb  = (u16*)(ws + 8 * MB);    // bf16 value-input; later reused as Op
  u16* Qp  = (u16*)(ws + 16 * MB);
  u16* Kp  = (u16*)(ws + 24 * MB);
  u16* VpT = (u16*)(ws + 32 * MB);   // V^T [1024][4096]
  u16* Op  = (u16*)(ws + 8 * MB);    // reuse Vb space (dead after QKV GEMM)
  // bf16 query/key inputs parked in d_out (16MB; overwritten by final GEMM)
  u16* Qb = (u16*)d_out;
  u16* Kb = (u16*)d_out + (size_t)4 * MB;   // element offset: 8MB bytes

  ConvA ca;
  ca.src[0] = (const float*)d_in[0]; ca.dst[0] = Qb;
  ca.src[1] = (const float*)d_in[1]; ca.dst[1] = Kb;
  ca.src[2] = (const float*)d_in[2]; ca.dst[2] = Vb;
  hipLaunchKernelGGL(convA, dim3(2048, 1, 3), dim3(256), 0, stream, ca);

  TransA ta;
  ta.W[0] = (const float*)d_in[3]; ta.Wt[0] = Wqt;
  ta.W[1] = (const float*)d_in[5]; ta.Wt[1] = Wkt;
  ta.W[2] = (const float*)d_in[7]; ta.Wt[2] = Wvt;
  ta.W[3] = (const float*)d_in[9]; ta.Wt[3] = Wot;
  hipLaunchKernelGGL(transW, dim3(16, 16, 4), dim3(256), 0, stream, ta);

  GemmB gp;
  gp.A[0] = Qb; gp.Bt[0] = Wqt; gp.bias[0] = (const float*)d_in[4]; gp.C[0] = Qp;  gp.mode[0] = 0;
  gp.A[1] = Kb; gp.Bt[1] = Wkt; gp.bias[1] = (const float*)d_in[6]; gp.C[1] = Kp;  gp.mode[1] = 0;
  gp.A[2] = Vb; gp.Bt[2] = Wvt; gp.bias[2] = (const float*)d_in[8]; gp.C[2] = VpT; gp.mode[2] = 2;
  gp.cpx = 96;
  hipLaunchKernelGGL(gemm_bt, dim3(768), dim3(256), 0, stream, gp);

  hipLaunchKernelGGL(attn_fwd, dim3(1024), dim3(256), 0, stream, Qp, Kp, VpT, Op);

  GemmB gf;
  gf.A[0] = Op; gf.Bt[0] = Wot; gf.bias[0] = (const float*)d_in[10]; gf.C[0] = (void*)d_out; gf.mode[0] = 1;
  gf.A[1] = nullptr; gf.A[2] = nullptr; gf.Bt[1] = nullptr; gf.Bt[2] = nullptr;
  gf.bias[1] = nullptr; gf.bias[2] = nullptr; gf.C[1] = nullptr; gf.C[2] = nullptr;
  gf.mode[1] = 0; gf.mode[2] = 0;
  gf.cpx = 32;
  hipLaunchKernelGGL(gemm_bt, dim3(256), dim3(256), 0, stream, gf);
}

// Round 6
// 165.270 us; speedup vs baseline: 1.4422x; 1.4422x over previous
//
#include <hip/hip_runtime.h>

typedef unsigned short u16;
typedef unsigned int   u32;
typedef __bf16 bf16x8 __attribute__((ext_vector_type(8)));
typedef float  f32x4  __attribute__((ext_vector_type(4)));

union U16B { int4 i4; bf16x8 b8; u16 u[8]; };
union U16Q { uint2 d2; u16 u[4]; };

static __device__ __forceinline__ u16 f2b(float f) {
  u32 x = __float_as_uint(f);
  x += 0x7FFFu + ((x >> 16) & 1u);   // RNE (inputs finite)
  return (u16)(x >> 16);
}
static __device__ __forceinline__ float b2f(u16 s) {
  return __uint_as_float(((u32)s) << 16);
}

// ---------------- fp32 -> bf16 convert (inputs, once) ----------------
struct ConvA { const float* src[3]; u16* dst[3]; };

__global__ __launch_bounds__(256) void convA(ConvA a) {
  const float* s = a.src[blockIdx.z];
  u16*         d = a.dst[blockIdx.z];
  const size_t i = ((size_t)blockIdx.x * 256 + threadIdx.x) * 8;
  float4 f0 = *(const float4*)(s + i);
  float4 f1 = *(const float4*)(s + i + 4);
  U16B t;
  t.u[0] = f2b(f0.x); t.u[1] = f2b(f0.y); t.u[2] = f2b(f0.z); t.u[3] = f2b(f0.w);
  t.u[4] = f2b(f1.x); t.u[5] = f2b(f1.y); t.u[6] = f2b(f1.z); t.u[7] = f2b(f1.w);
  *(int4*)(d + i) = t.i4;
}

// ---------------- weight transpose + fp32->bf16 convert ----------------
struct TransA { const float* W[4]; u16* Wt[4]; };

__global__ __launch_bounds__(256) void transW(TransA a) {
  const float* W  = a.W[blockIdx.z];
  u16*         Wt = a.Wt[blockIdx.z];
  __shared__ float t[64][65];
  const int bx = blockIdx.x * 64, by = blockIdx.y * 64;
  const int tx = threadIdx.x & 63, ty = threadIdx.x >> 6;
  #pragma unroll
  for (int j = 0; j < 16; ++j) {
    int row = j * 4 + ty;
    t[row][tx] = W[(size_t)(by + row) * 1024 + bx + tx];
  }
  __syncthreads();
  #pragma unroll
  for (int j = 0; j < 16; ++j) {
    int row = j * 4 + ty;           // Wt[n][k] = W[k][n]
    Wt[(size_t)(bx + row) * 1024 + by + tx] = f2b(t[tx][row]);
  }
}

// ---------------- GEMM: C = A[M][K](bf16) * Bt[N][K]^T + bias ----------------
// 128x128 tile, BK=64, 4 waves, XOR-swizzled LDS. Flat grid with XCD swizzle:
// logical = (bid%8)*cpx + bid/8; 256 logical blocks per z (8 x * 32 y).
// mode: 0=bf16 row-major, 1=f32 row-major, 2=bf16 transposed C^T[N][4096].
struct GemmB { const u16* A[3]; const u16* Bt[3]; const float* bias[3]; void* C[3]; int mode[3]; int cpx; };

__global__ __launch_bounds__(256) void gemm_bt(GemmB g) {
  constexpr int K = 1024, N = 1024;
  __shared__ u16 As[128 * 64];
  __shared__ u16 Bs[128 * 64];
  const int bid = blockIdx.x;
  const int lg = (bid & 7) * g.cpx + (bid >> 3);
  const int z = lg >> 8;
  const int rem = lg & 255;
  const int row0 = (rem >> 3) * 128, col0 = (rem & 7) * 128;
  const u16*   Ap   = g.A[z];
  const u16*   Bt   = g.Bt[z];
  const float* bias = g.bias[z];
  const int mode = g.mode[z];
  const int tid = threadIdx.x;
  const int wid = tid >> 6, lane = tid & 63;
  const int wr = wid >> 1, wc = wid & 1;
  const int lo = lane & 15, hi = lane >> 4;
  const int rs = tid >> 3, us = tid & 7;

  f32x4 acc[4][4];
  const f32x4 z4 = {0.f, 0.f, 0.f, 0.f};
  #pragma unroll
  for (int i = 0; i < 4; ++i)
    #pragma unroll
    for (int j = 0; j < 4; ++j) acc[i][j] = z4;

  for (int kt = 0; kt < K / 64; ++kt) {
    __syncthreads();
    #pragma unroll
    for (int c = 0; c < 4; ++c) {
      int r = c * 32 + rs;
      int lds = r * 64 + ((us ^ (r & 7)) << 3);
      *(int4*)&As[lds] = *(const int4*)(Ap + (size_t)(row0 + r) * K + kt * 64 + us * 8);
      *(int4*)&Bs[lds] = *(const int4*)(Bt + (size_t)(col0 + r) * K + kt * 64 + us * 8);
    }
    __syncthreads();
    #pragma unroll
    for (int ks = 0; ks < 2; ++ks) {
      bf16x8 af[4], bfr[4];
      #pragma unroll
      for (int mf = 0; mf < 4; ++mf) {
        int r = wr * 64 + mf * 16 + lo;
        af[mf] = *(const bf16x8*)&As[r * 64 + (((ks * 4 + hi) ^ (r & 7)) << 3)];
      }
      #pragma unroll
      for (int nf = 0; nf < 4; ++nf) {
        int r = wc * 64 + nf * 16 + lo;
        bfr[nf] = *(const bf16x8*)&Bs[r * 64 + (((ks * 4 + hi) ^ (r & 7)) << 3)];
      }
      #pragma unroll
      for (int mf = 0; mf < 4; ++mf)
        #pragma unroll
        for (int nf = 0; nf < 4; ++nf)
          acc[mf][nf] = __builtin_amdgcn_mfma_f32_16x16x32_bf16(af[mf], bfr[nf], acc[mf][nf], 0, 0, 0);
    }
  }

  #pragma unroll
  for (int nf = 0; nf < 4; ++nf) {
    int col = col0 + wc * 64 + nf * 16 + lo;
    float bv = bias[col];
    #pragma unroll
    for (int mf = 0; mf < 4; ++mf) {
      int rb = row0 + wr * 64 + mf * 16 + hi * 4;   // C/D: row=(l>>4)*4+e, col=l&15
      if (mode == 2) {
        U16Q q4;
        #pragma unroll
        for (int e = 0; e < 4; ++e) q4.u[e] = f2b(acc[mf][nf][e] + bv);
        *(uint2*)&((u16*)g.C[z])[(size_t)col * 4096 + rb] = q4.d2;   // C^T[N][4096]
      } else {
        #pragma unroll
        for (int e = 0; e < 4; ++e) {
          float v = acc[mf][nf][e] + bv;
          if (mode == 1) ((float*)g.C[z])[(size_t)(rb + e) * N + col] = v;
          else           ((u16*)g.C[z])[(size_t)(rb + e) * N + col] = f2b(v);
        }
      }
    }
  }
}

// ---------------- flash attention ----------------
// BYTE-EXACT round-3 kernel (validated 84.5us, VGPR=56, WRITE_SIZE=8MB).
// R4/R5 "improvements" (early-issue loads / PK4 / defer-max) triggered
// scratch spills: VGPR dropped to 48, WRITE_SIZE blew up to 88MB, dur 2x.
// Short live ranges (fused load+store staging after the barrier) are what
// keeps the allocator spill-free here. Do not extend liveness across barriers.
__global__ __launch_bounds__(256) void attn_fwd(const u16* __restrict__ Q,
                                                const u16* __restrict__ Kp,
                                                const u16* __restrict__ VpT,
                                                u16* __restrict__ O) {
  __shared__ u16 Ks[64 * 64];    // K tile [kk][d], XOR-swizzled rows
  __shared__ u16 Vts[64 * 64];   // V^T tile [d][kk], XOR-swizzled rows
  __shared__ u16 Ps[64 * 64];    // P tile [q][kk], XOR-swizzled rows
  const int tid = threadIdx.x;
  // XCD-aware decode: xcd = bid&7 owns 4 (h,b) pairs -> K/V L2-resident
  const int bid = blockIdx.x;
  const int t = bid >> 3;
  const int hb = (bid & 7) * 4 + (t >> 5);
  const int qb = t & 31;
  const int h = hb & 15, b = hb >> 4;
  const int wid = tid >> 6, lane = tid & 63;
  const int lo = lane & 15, hi = lane >> 4;
  const int rs = tid >> 3, us = tid & 7;
  const int hoff = h * 64;
  const size_t rowQ0 = (size_t)b * 2048 + (size_t)qb * 64;
  const float QSCALE = 0.125f * 1.4426950408889634f;

  // Q fragments (B-operand): lane holds Q[q = wid*16+lo][d = ks*32 + hi*8 .. +8]
  bf16x8 qf[2];
  #pragma unroll
  for (int ks = 0; ks < 2; ++ks) {
    size_t r = rowQ0 + wid * 16 + lo;
    U16B in; in.i4 = *(const int4*)&Q[r * 1024 + hoff + ks * 32 + hi * 8];
    U16B o;
    #pragma unroll
    for (int j = 0; j < 8; ++j) o.u[j] = f2b(b2f(in.u[j]) * QSCALE);
    qf[ks] = o.b8;
  }

  f32x4 oacc[4];
  const f32x4 z4 = {0.f, 0.f, 0.f, 0.f};
  #pragma unroll
  for (int df = 0; df < 4; ++df) oacc[df] = z4;
  float m_r = -1e30f, l_r = 0.f;   // row stats for q = wid*16+lo (replicated over hi)

  for (int kb = 0; kb < 32; ++kb) {
    const int kv0 = kb * 64;
    __syncthreads();
    #pragma unroll
    for (int c = 0; c < 2; ++c) {
      int r = c * 32 + rs;
      int lds = r * 64 + ((us ^ (r & 7)) << 3);
      *(int4*)&Ks[lds]  = *(const int4*)&Kp[((size_t)b * 2048 + kv0 + r) * 1024 + hoff + us * 8];
      *(int4*)&Vts[lds] = *(const int4*)&VpT[(size_t)(hoff + r) * 4096 + b * 2048 + kv0 + us * 8];
    }
    __syncthreads();

    // S^T = K Q^T : frag nf covers kk = nf*16 + hi*4 + e, q = wid*16+lo
    f32x4 sfr[4];
    #pragma unroll
    for (int nf = 0; nf < 4; ++nf) sfr[nf] = z4;
    #pragma unroll
    for (int ks = 0; ks < 2; ++ks) {
      #pragma unroll
      for (int nf = 0; nf < 4; ++nf) {
        int kk = nf * 16 + lo;
        bf16x8 kf = *(const bf16x8*)&Ks[kk * 64 + (((ks * 4 + hi) ^ (kk & 7)) << 3)];
        sfr[nf] = __builtin_amdgcn_mfma_f32_16x16x32_bf16(kf, qf[ks], sfr[nf], 0, 0, 0);
      }
    }

    // online softmax (16 values per lane, reduce over hi via 2 shfl)
    float pm = -1e30f;
    #pragma unroll
    for (int nf = 0; nf < 4; ++nf)
      #pragma unroll
      for (int e = 0; e < 4; ++e) pm = fmaxf(pm, sfr[nf][e]);
    pm = fmaxf(pm, __shfl_xor(pm, 16));
    pm = fmaxf(pm, __shfl_xor(pm, 32));
    float mn = fmaxf(m_r, pm);
    float cc = __builtin_amdgcn_exp2f(m_r - mn);
    m_r = mn;
    float ps = 0.f;
    #pragma unroll
    for (int nf = 0; nf < 4; ++nf) {
      U16Q pk;
      #pragma unroll
      for (int e = 0; e < 4; ++e) {
        float p = __builtin_amdgcn_exp2f(sfr[nf][e] - mn);
        ps += p;
        pk.u[e] = f2b(p);
      }
      *(uint2*)&Ps[(wid * 16 + lo) * 64 + ((nf * 16 + hi * 4) ^ ((lo & 7) << 3))] = pk.d2;
    }
    ps += __shfl_xor(ps, 16);
    ps += __shfl_xor(ps, 32);
    l_r = l_r * cc + ps;
    float cce[4];
    #pragma unroll
    for (int e = 0; e < 4; ++e) cce[e] = __shfl(cc, hi * 4 + e);
    __syncthreads();

    // O = O*cc + P V
    #pragma unroll
    for (int ksp = 0; ksp < 2; ++ksp) {
      bf16x8 pa = *(const bf16x8*)&Ps[(wid * 16 + lo) * 64 + ((((ksp * 4 + hi) ^ (lo & 7))) << 3)];
      bf16x8 vb[4];
      #pragma unroll
      for (int df = 0; df < 4; ++df) {
        int d = df * 16 + lo;
        vb[df] = *(const bf16x8*)&Vts[d * 64 + (((ksp * 4 + hi) ^ (d & 7)) << 3)];
      }
      if (ksp == 0) {
        #pragma unroll
        for (int df = 0; df < 4; ++df)
          #pragma unroll
          for (int e = 0; e < 4; ++e) oacc[df][e] *= cce[e];
      }
      #pragma unroll
      for (int df = 0; df < 4; ++df)
        oacc[df] = __builtin_amdgcn_mfma_f32_16x16x32_bf16(pa, vb[df], oacc[df], 0, 0, 0);
    }
  }

  // epilogue: normalize (stats live at q=wid*16+lo; O rows are q=hi*4+e -> gather)
  float inv = __builtin_amdgcn_rcpf(l_r);
  float inve[4];
  #pragma unroll
  for (int e = 0; e < 4; ++e) inve[e] = __shfl(inv, hi * 4 + e);
  #pragma unroll
  for (int df = 0; df < 4; ++df)
    #pragma unroll
    for (int e = 0; e < 4; ++e) {
      size_t row = rowQ0 + wid * 16 + hi * 4 + e;
      O[row * 1024 + hoff + df * 16 + lo] = f2b(oacc[df][e] * inve[e]);
    }
}

// ---------------- launch ----------------
extern "C" void kernel_launch(void* const* d_in, const int* in_sizes, int n_in,
                              void* d_out, int out_size, void* d_ws, size_t ws_size,
                              hipStream_t stream) {
  (void)in_sizes; (void)n_in; (void)out_size;
  const size_t MB = 1024 * 1024;
  if (ws_size < 40 * MB) return;
  char* ws = (char*)d_ws;
  u16* Wqt = (u16*)(ws + 0 * MB);
  u16* Wkt = (u16*)(ws + 2 * MB);
  u16* Wvt = (u16*)(ws + 4 * MB);
  u16* Wot = (u16*)(ws + 6 * MB);
  u16* Vb  = (u16*)(ws + 8 * MB);    // bf16 value-input; later reused as Op
  u16* Qp  = (u16*)(ws + 16 * MB);
  u16* Kp  = (u16*)(ws + 24 * MB);
  u16* VpT = (u16*)(ws + 32 * MB);   // V^T [1024][4096]
  u16* Op  = (u16*)(ws + 8 * MB);    // reuse Vb space (dead after QKV GEMM)
  // bf16 query/key inputs parked in d_out (16MB; overwritten by final GEMM)
  u16* Qb = (u16*)d_out;
  u16* Kb = (u16*)d_out + (size_t)4 * MB;   // element offset: 8MB bytes

  ConvA ca;
  ca.src[0] = (const float*)d_in[0]; ca.dst[0] = Qb;
  ca.src[1] = (const float*)d_in[1]; ca.dst[1] = Kb;
  ca.src[2] = (const float*)d_in[2]; ca.dst[2] = Vb;
  hipLaunchKernelGGL(convA, dim3(2048, 1, 3), dim3(256), 0, stream, ca);

  TransA ta;
  ta.W[0] = (const float*)d_in[3]; ta.Wt[0] = Wqt;
  ta.W[1] = (const float*)d_in[5]; ta.Wt[1] = Wkt;
  ta.W[2] = (const float*)d_in[7]; ta.Wt[2] = Wvt;
  ta.W[3] = (const float*)d_in[9]; ta.Wt[3] = Wot;
  hipLaunchKernelGGL(transW, dim3(16, 16, 4), dim3(256), 0, stream, ta);

  GemmB gp;
  gp.A[0] = Qb; gp.Bt[0] = Wqt; gp.bias[0] = (const float*)d_in[4]; gp.C[0] = Qp;  gp.mode[0] = 0;
  gp.A[1] = Kb; gp.Bt[1] = Wkt; gp.bias[1] = (const float*)d_in[6]; gp.C[1] = Kp;  gp.mode[1] = 0;
  gp.A[2] = Vb; gp.Bt[2] = Wvt; gp.bias[2] = (const float*)d_in[8]; gp.C[2] = VpT; gp.mode[2] = 2;
  gp.cpx = 96;
  hipLaunchKernelGGL(gemm_bt, dim3(768), dim3(256), 0, stream, gp);

  hipLaunchKernelGGL(attn_fwd, dim3(1024), dim3(256), 0, stream, Qp, Kp, VpT, Op);

  GemmB gf;
  gf.A[0] = Op; gf.Bt[0] = Wot; gf.bias[0] = (const float*)d_in[10]; gf.C[0] = (void*)d_out; gf.mode[0] = 1;
  gf.A[1] = nullptr; gf.A[2] = nullptr; gf.Bt[1] = nullptr; gf.Bt[2] = nullptr;
  gf.bias[1] = nullptr; gf.bias[2] = nullptr; gf.C[1] = nullptr; gf.C[2] = nullptr;
  gf.mode[1] = 0; gf.mode[2] = 0;
  gf.cpx = 32;
  hipLaunchKernelGGL(gemm_bt, dim3(256), dim3(256), 0, stream, gf);
}

// Round 7
// 159.560 us; speedup vs baseline: 1.4938x; 1.0358x over previous
//
#include <hip/hip_runtime.h>

typedef unsigned short u16;
typedef unsigned int   u32;
typedef __bf16 bf16x8 __attribute__((ext_vector_type(8)));
typedef float  f32x4  __attribute__((ext_vector_type(4)));

union U16B { int4 i4; bf16x8 b8; u16 u[8]; };
union U16Q { uint2 d2; u16 u[4]; };
union PK4  { uint2 d2; __bf16 b[4]; };

static __device__ __forceinline__ u16 f2b(float f) {
  u32 x = __float_as_uint(f);
  x += 0x7FFFu + ((x >> 16) & 1u);   // RNE (inputs finite)
  return (u16)(x >> 16);
}
static __device__ __forceinline__ float b2f(u16 s) {
  return __uint_as_float(((u32)s) << 16);
}

// async global->LDS: dest must be linear (wave-uniform base + lane*16)
#define GLOAD_LDS16(g, l) \
  __builtin_amdgcn_global_load_lds((const __attribute__((address_space(1))) u32*)(g), \
                                   (__attribute__((address_space(3))) u32*)(l), 16, 0, 0)

// ---------------- fp32 -> bf16 convert (inputs, once) ----------------
struct ConvA { const float* src[3]; u16* dst[3]; };

__global__ __launch_bounds__(256) void convA(ConvA a) {
  const float* s = a.src[blockIdx.z];
  u16*         d = a.dst[blockIdx.z];
  const size_t i = ((size_t)blockIdx.x * 256 + threadIdx.x) * 8;
  float4 f0 = *(const float4*)(s + i);
  float4 f1 = *(const float4*)(s + i + 4);
  U16B t;
  t.u[0] = f2b(f0.x); t.u[1] = f2b(f0.y); t.u[2] = f2b(f0.z); t.u[3] = f2b(f0.w);
  t.u[4] = f2b(f1.x); t.u[5] = f2b(f1.y); t.u[6] = f2b(f1.z); t.u[7] = f2b(f1.w);
  *(int4*)(d + i) = t.i4;
}

// ---------------- weight transpose + fp32->bf16 convert ----------------
struct TransA { const float* W[4]; u16* Wt[4]; };

__global__ __launch_bounds__(256) void transW(TransA a) {
  const float* W  = a.W[blockIdx.z];
  u16*         Wt = a.Wt[blockIdx.z];
  __shared__ float t[64][65];
  const int bx = blockIdx.x * 64, by = blockIdx.y * 64;
  const int tx = threadIdx.x & 63, ty = threadIdx.x >> 6;
  #pragma unroll
  for (int j = 0; j < 16; ++j) {
    int row = j * 4 + ty;
    t[row][tx] = W[(size_t)(by + row) * 1024 + bx + tx];
  }
  __syncthreads();
  #pragma unroll
  for (int j = 0; j < 16; ++j) {
    int row = j * 4 + ty;           // Wt[n][k] = W[k][n]
    Wt[(size_t)(bx + row) * 1024 + by + tx] = f2b(t[tx][row]);
  }
}

// ---------------- GEMM: C = A[M][K](bf16) * Bt[N][K]^T + bias ----------------
// 128x128 tile, BK=64, 4 waves, m97 2-barrier structure. Staging via
// global_load_lds width=16: LDS dest LINEAR (base + tid*16B), global source
// pre-swizzled by us^(rs&7) (XOR involution) so the swizzled ds_read_b128
// fragment reads see a conflict-free layout (rule #21: both-sides-or-neither).
// mode: 0=bf16 row-major, 1=f32 row-major, 2=bf16 transposed C^T[N][4096].
struct GemmB { const u16* A[3]; const u16* Bt[3]; const float* bias[3]; void* C[3]; int mode[3]; int cpx; };

__global__ __launch_bounds__(256) void gemm_bt(GemmB g) {
  constexpr int K = 1024, N = 1024;
  __shared__ u16 As[128 * 64];
  __shared__ u16 Bs[128 * 64];
  const int bid = blockIdx.x;
  const int lg = (bid & 7) * g.cpx + (bid >> 3);
  const int z = lg >> 8;
  const int rem = lg & 255;
  const int row0 = (rem >> 3) * 128, col0 = (rem & 7) * 128;
  const u16*   Ap   = g.A[z];
  const u16*   Bt   = g.Bt[z];
  const float* bias = g.bias[z];
  const int mode = g.mode[z];
  const int tid = threadIdx.x;
  const int wid = tid >> 6, lane = tid & 63;
  const int wr = wid >> 1, wc = wid & 1;
  const int lo = lane & 15, hi = lane >> 4;
  const int rs = tid >> 3, us = tid & 7;
  const int sw = (us ^ (rs & 7)) * 8;   // pre-swizzled source column unit

  f32x4 acc[4][4];
  const f32x4 z4 = {0.f, 0.f, 0.f, 0.f};
  #pragma unroll
  for (int i = 0; i < 4; ++i)
    #pragma unroll
    for (int j = 0; j < 4; ++j) acc[i][j] = z4;

  for (int kt = 0; kt < K / 64; ++kt) {
    __syncthreads();
    #pragma unroll
    for (int c = 0; c < 4; ++c) {
      int r = c * 32 + rs;
      GLOAD_LDS16(Ap + (size_t)(row0 + r) * K + kt * 64 + sw, &As[r * 64 + us * 8]);
      GLOAD_LDS16(Bt + (size_t)(col0 + r) * K + kt * 64 + sw, &Bs[r * 64 + us * 8]);
    }
    __syncthreads();   // compiler drains vmcnt before s_barrier
    #pragma unroll
    for (int ks = 0; ks < 2; ++ks) {
      bf16x8 af[4], bfr[4];
      #pragma unroll
      for (int mf = 0; mf < 4; ++mf) {
        int r = wr * 64 + mf * 16 + lo;
        af[mf] = *(const bf16x8*)&As[r * 64 + (((ks * 4 + hi) ^ (r & 7)) << 3)];
      }
      #pragma unroll
      for (int nf = 0; nf < 4; ++nf) {
        int r = wc * 64 + nf * 16 + lo;
        bfr[nf] = *(const bf16x8*)&Bs[r * 64 + (((ks * 4 + hi) ^ (r & 7)) << 3)];
      }
      #pragma unroll
      for (int mf = 0; mf < 4; ++mf)
        #pragma unroll
        for (int nf = 0; nf < 4; ++nf)
          acc[mf][nf] = __builtin_amdgcn_mfma_f32_16x16x32_bf16(af[mf], bfr[nf], acc[mf][nf], 0, 0, 0);
    }
  }

  #pragma unroll
  for (int nf = 0; nf < 4; ++nf) {
    int col = col0 + wc * 64 + nf * 16 + lo;
    float bv = bias[col];
    #pragma unroll
    for (int mf = 0; mf < 4; ++mf) {
      int rb = row0 + wr * 64 + mf * 16 + hi * 4;   // C/D: row=(l>>4)*4+e, col=l&15
      if (mode == 2) {
        U16Q q4;
        #pragma unroll
        for (int e = 0; e < 4; ++e) q4.u[e] = f2b(acc[mf][nf][e] + bv);
        *(uint2*)&((u16*)g.C[z])[(size_t)col * 4096 + rb] = q4.d2;   // C^T[N][4096]
      } else {
        #pragma unroll
        for (int e = 0; e < 4; ++e) {
          float v = acc[mf][nf][e] + bv;
          if (mode == 1) ((float*)g.C[z])[(size_t)(rb + e) * N + col] = v;
          else           ((u16*)g.C[z])[(size_t)(rb + e) * N + col] = f2b(v);
        }
      }
    }
  }
}

// ---------------- flash attention ----------------
// Round-3 structure (validated 84.5us, VGPR=56, WRITE=8MB). ONE change vs R6:
// P-pack uses native __bf16 casts (PK4) instead of f2b bit-twiddle — isolates
// whether PK4 was R5's spill trigger. Everything else byte-identical.
__global__ __launch_bounds__(256) void attn_fwd(const u16* __restrict__ Q,
                                                const u16* __restrict__ Kp,
                                                const u16* __restrict__ VpT,
                                                u16* __restrict__ O) {
  __shared__ u16 Ks[64 * 64];    // K tile [kk][d], XOR-swizzled rows
  __shared__ u16 Vts[64 * 64];   // V^T tile [d][kk], XOR-swizzled rows
  __shared__ u16 Ps[64 * 64];    // P tile [q][kk], XOR-swizzled rows
  const int tid = threadIdx.x;
  // XCD-aware decode: xcd = bid&7 owns 4 (h,b) pairs -> K/V L2-resident
  const int bid = blockIdx.x;
  const int t = bid >> 3;
  const int hb = (bid & 7) * 4 + (t >> 5);
  const int qb = t & 31;
  const int h = hb & 15, b = hb >> 4;
  const int wid = tid >> 6, lane = tid & 63;
  const int lo = lane & 15, hi = lane >> 4;
  const int rs = tid >> 3, us = tid & 7;
  const int hoff = h * 64;
  const size_t rowQ0 = (size_t)b * 2048 + (size_t)qb * 64;
  const float QSCALE = 0.125f * 1.4426950408889634f;

  // Q fragments (B-operand): lane holds Q[q = wid*16+lo][d = ks*32 + hi*8 .. +8]
  bf16x8 qf[2];
  #pragma unroll
  for (int ks = 0; ks < 2; ++ks) {
    size_t r = rowQ0 + wid * 16 + lo;
    U16B in; in.i4 = *(const int4*)&Q[r * 1024 + hoff + ks * 32 + hi * 8];
    U16B o;
    #pragma unroll
    for (int j = 0; j < 8; ++j) o.u[j] = f2b(b2f(in.u[j]) * QSCALE);
    qf[ks] = o.b8;
  }

  f32x4 oacc[4];
  const f32x4 z4 = {0.f, 0.f, 0.f, 0.f};
  #pragma unroll
  for (int df = 0; df < 4; ++df) oacc[df] = z4;
  float m_r = -1e30f, l_r = 0.f;   // row stats for q = wid*16+lo (replicated over hi)

  for (int kb = 0; kb < 32; ++kb) {
    const int kv0 = kb * 64;
    __syncthreads();
    #pragma unroll
    for (int c = 0; c < 2; ++c) {
      int r = c * 32 + rs;
      int lds = r * 64 + ((us ^ (r & 7)) << 3);
      *(int4*)&Ks[lds]  = *(const int4*)&Kp[((size_t)b * 2048 + kv0 + r) * 1024 + hoff + us * 8];
      *(int4*)&Vts[lds] = *(const int4*)&VpT[(size_t)(hoff + r) * 4096 + b * 2048 + kv0 + us * 8];
    }
    __syncthreads();

    // S^T = K Q^T : frag nf covers kk = nf*16 + hi*4 + e, q = wid*16+lo
    f32x4 sfr[4];
    #pragma unroll
    for (int nf = 0; nf < 4; ++nf) sfr[nf] = z4;
    #pragma unroll
    for (int ks = 0; ks < 2; ++ks) {
      #pragma unroll
      for (int nf = 0; nf < 4; ++nf) {
        int kk = nf * 16 + lo;
        bf16x8 kf = *(const bf16x8*)&Ks[kk * 64 + (((ks * 4 + hi) ^ (kk & 7)) << 3)];
        sfr[nf] = __builtin_amdgcn_mfma_f32_16x16x32_bf16(kf, qf[ks], sfr[nf], 0, 0, 0);
      }
    }

    // online softmax (16 values per lane, reduce over hi via 2 shfl)
    float pm = -1e30f;
    #pragma unroll
    for (int nf = 0; nf < 4; ++nf)
      #pragma unroll
      for (int e = 0; e < 4; ++e) pm = fmaxf(pm, sfr[nf][e]);
    pm = fmaxf(pm, __shfl_xor(pm, 16));
    pm = fmaxf(pm, __shfl_xor(pm, 32));
    float mn = fmaxf(m_r, pm);
    float cc = __builtin_amdgcn_exp2f(m_r - mn);
    m_r = mn;
    float ps = 0.f;
    #pragma unroll
    for (int nf = 0; nf < 4; ++nf) {
      PK4 pk;
      #pragma unroll
      for (int e = 0; e < 4; ++e) {
        float p = __builtin_amdgcn_exp2f(sfr[nf][e] - mn);
        ps += p;
        pk.b[e] = (__bf16)p;     // native cast -> packed cvt, replaces f2b bit-ops
      }
      *(uint2*)&Ps[(wid * 16 + lo) * 64 + ((nf * 16 + hi * 4) ^ ((lo & 7) << 3))] = pk.d2;
    }
    ps += __shfl_xor(ps, 16);
    ps += __shfl_xor(ps, 32);
    l_r = l_r * cc + ps;
    float cce[4];
    #pragma unroll
    for (int e = 0; e < 4; ++e) cce[e] = __shfl(cc, hi * 4 + e);
    __syncthreads();

    // O = O*cc + P V
    #pragma unroll
    for (int ksp = 0; ksp < 2; ++ksp) {
      bf16x8 pa = *(const bf16x8*)&Ps[(wid * 16 + lo) * 64 + ((((ksp * 4 + hi) ^ (lo & 7))) << 3)];
      bf16x8 vb[4];
      #pragma unroll
      for (int df = 0; df < 4; ++df) {
        int d = df * 16 + lo;
        vb[df] = *(const bf16x8*)&Vts[d * 64 + (((ksp * 4 + hi) ^ (d & 7)) << 3)];
      }
      if (ksp == 0) {
        #pragma unroll
        for (int df = 0; df < 4; ++df)
          #pragma unroll
          for (int e = 0; e < 4; ++e) oacc[df][e] *= cce[e];
      }
      #pragma unroll
      for (int df = 0; df < 4; ++df)
        oacc[df] = __builtin_amdgcn_mfma_f32_16x16x32_bf16(pa, vb[df], oacc[df], 0, 0, 0);
    }
  }

  // epilogue: normalize (stats live at q=wid*16+lo; O rows are q=hi*4+e -> gather)
  float inv = __builtin_amdgcn_rcpf(l_r);
  float inve[4];
  #pragma unroll
  for (int e = 0; e < 4; ++e) inve[e] = __shfl(inv, hi * 4 + e);
  #pragma unroll
  for (int df = 0; df < 4; ++df)
    #pragma unroll
    for (int e = 0; e < 4; ++e) {
      size_t row = rowQ0 + wid * 16 + hi * 4 + e;
      O[row * 1024 + hoff + df * 16 + lo] = f2b(oacc[df][e] * inve[e]);
    }
}

// ---------------- launch ----------------
extern "C" void kernel_launch(void* const* d_in, const int* in_sizes, int n_in,
                              void* d_out, int out_size, void* d_ws, size_t ws_size,
                              hipStream_t stream) {
  (void)in_sizes; (void)n_in; (void)out_size;
  const size_t MB = 1024 * 1024;
  if (ws_size < 40 * MB) return;
  char* ws = (char*)d_ws;
  u16* Wqt = (u16*)(ws + 0 * MB);
  u16* Wkt = (u16*)(ws + 2 * MB);
  u16* Wvt = (u16*)(ws + 4 * MB);
  u16* Wot = (u16*)(ws + 6 * MB);
  u16* Vb  = (u16*)(ws + 8 * MB);    // bf16 value-input; later reused as Op
  u16* Qp  = (u16*)(ws + 16 * MB);
  u16* Kp  = (u16*)(ws + 24 * MB);
  u16* VpT = (u16*)(ws + 32 * MB);   // V^T [1024][4096]
  u16* Op  = (u16*)(ws + 8 * MB);    // reuse Vb space (dead after QKV GEMM)
  // bf16 query/key inputs parked in d_out (16MB; overwritten by final GEMM)
  u16* Qb = (u16*)d_out;
  u16* Kb = (u16*)d_out + (size_t)4 * MB;   // element offset: 8MB bytes

  ConvA ca;
  ca.src[0] = (const float*)d_in[0]; ca.dst[0] = Qb;
  ca.src[1] = (const float*)d_in[1]; ca.dst[1] = Kb;
  ca.src[2] = (const float*)d_in[2]; ca.dst[2] = Vb;
  hipLaunchKernelGGL(convA, dim3(2048, 1, 3), dim3(256), 0, stream, ca);

  TransA ta;
  ta.W[0] = (const float*)d_in[3]; ta.Wt[0] = Wqt;
  ta.W[1] = (const float*)d_in[5]; ta.Wt[1] = Wkt;
  ta.W[2] = (const float*)d_in[7]; ta.Wt[2] = Wvt;
  ta.W[3] = (const float*)d_in[9]; ta.Wt[3] = Wot;
  hipLaunchKernelGGL(transW, dim3(16, 16, 4), dim3(256), 0, stream, ta);

  GemmB gp;
  gp.A[0] = Qb; gp.Bt[0] = Wqt; gp.bias[0] = (const float*)d_in[4]; gp.C[0] = Qp;  gp.mode[0] = 0;
  gp.A[1] = Kb; gp.Bt[1] = Wkt; gp.bias[1] = (const float*)d_in[6]; gp.C[1] = Kp;  gp.mode[1] = 0;
  gp.A[2] = Vb; gp.Bt[2] = Wvt; gp.bias[2] = (const float*)d_in[8]; gp.C[2] = VpT; gp.mode[2] = 2;
  gp.cpx = 96;
  hipLaunchKernelGGL(gemm_bt, dim3(768), dim3(256), 0, stream, gp);

  hipLaunchKernelGGL(attn_fwd, dim3(1024), dim3(256), 0, stream, Qp, Kp, VpT, Op);

  GemmB gf;
  gf.A[0] = Op; gf.Bt[0] = Wot; gf.bias[0] = (const float*)d_in[10]; gf.C[0] = (void*)d_out; gf.mode[0] = 1;
  gf.A[1] = nullptr; gf.A[2] = nullptr; gf.Bt[1] = nullptr; gf.Bt[2] = nullptr;
  gf.bias[1] = nullptr; gf.bias[2] = nullptr; gf.C[1] = nullptr; gf.C[2] = nullptr;
  gf.mode[1] = 0; gf.mode[2] = 0;
  gf.cpx = 32;
  hipLaunchKernelGGL(gemm_bt, dim3(256), dim3(256), 0, stream, gf);
}

// Round 8
// 159.000 us; speedup vs baseline: 1.4990x; 1.0035x over previous
//
#include <hip/hip_runtime.h>

typedef unsigned short u16;
typedef unsigned int   u32;
typedef __bf16 bf16x8 __attribute__((ext_vector_type(8)));
typedef float  f32x4  __attribute__((ext_vector_type(4)));

union U16B { int4 i4; bf16x8 b8; u16 u[8]; };
union U16Q { uint2 d2; u16 u[4]; };
union PK4  { uint2 d2; __bf16 b[4]; };

static __device__ __forceinline__ u16 f2b(float f) {
  u32 x = __float_as_uint(f);
  x += 0x7FFFu + ((x >> 16) & 1u);   // RNE (inputs finite)
  return (u16)(x >> 16);
}
static __device__ __forceinline__ float b2f(u16 s) {
  return __uint_as_float(((u32)s) << 16);
}

// async global->LDS: dest must be linear (wave-uniform base + lane*16)
#define GLOAD_LDS16(g, l) \
  __builtin_amdgcn_global_load_lds((const __attribute__((address_space(1))) u32*)(g), \
                                   (__attribute__((address_space(3))) u32*)(l), 16, 0, 0)

// ---------------- fp32 -> bf16 convert (inputs, once) ----------------
struct ConvA { const float* src[3]; u16* dst[3]; };

__global__ __launch_bounds__(256) void convA(ConvA a) {
  const float* s = a.src[blockIdx.z];
  u16*         d = a.dst[blockIdx.z];
  const size_t i = ((size_t)blockIdx.x * 256 + threadIdx.x) * 8;
  float4 f0 = *(const float4*)(s + i);
  float4 f1 = *(const float4*)(s + i + 4);
  U16B t;
  t.u[0] = f2b(f0.x); t.u[1] = f2b(f0.y); t.u[2] = f2b(f0.z); t.u[3] = f2b(f0.w);
  t.u[4] = f2b(f1.x); t.u[5] = f2b(f1.y); t.u[6] = f2b(f1.z); t.u[7] = f2b(f1.w);
  *(int4*)(d + i) = t.i4;
}

// ---------------- weight transpose + fp32->bf16 convert ----------------
struct TransA { const float* W[4]; u16* Wt[4]; };

__global__ __launch_bounds__(256) void transW(TransA a) {
  const float* W  = a.W[blockIdx.z];
  u16*         Wt = a.Wt[blockIdx.z];
  __shared__ float t[64][65];
  const int bx = blockIdx.x * 64, by = blockIdx.y * 64;
  const int tx = threadIdx.x & 63, ty = threadIdx.x >> 6;
  #pragma unroll
  for (int j = 0; j < 16; ++j) {
    int row = j * 4 + ty;
    t[row][tx] = W[(size_t)(by + row) * 1024 + bx + tx];
  }
  __syncthreads();
  #pragma unroll
  for (int j = 0; j < 16; ++j) {
    int row = j * 4 + ty;           // Wt[n][k] = W[k][n]
    Wt[(size_t)(bx + row) * 1024 + by + tx] = f2b(t[tx][row]);
  }
}

// ---------------- GEMM: C = A[M][K](bf16) * Bt[N][K]^T + bias ----------------
// 128x128 tile, BK=64, 4 waves, m97 2-barrier structure. Staging via
// global_load_lds width=16: LDS dest LINEAR (base + tid*16B), global source
// pre-swizzled by us^(rs&7) (XOR involution) so the swizzled ds_read_b128
// fragment reads see a conflict-free layout (rule #21: both-sides-or-neither).
// mode: 0=bf16 row-major, 1=f32 row-major, 2=bf16 transposed C^T[N][4096].
struct GemmB { const u16* A[3]; const u16* Bt[3]; const float* bias[3]; void* C[3]; int mode[3]; int cpx; };

__global__ __launch_bounds__(256) void gemm_bt(GemmB g) {
  constexpr int K = 1024, N = 1024;
  __shared__ u16 As[128 * 64];
  __shared__ u16 Bs[128 * 64];
  const int bid = blockIdx.x;
  const int lg = (bid & 7) * g.cpx + (bid >> 3);
  const int z = lg >> 8;
  const int rem = lg & 255;
  const int row0 = (rem >> 3) * 128, col0 = (rem & 7) * 128;
  const u16*   Ap   = g.A[z];
  const u16*   Bt   = g.Bt[z];
  const float* bias = g.bias[z];
  const int mode = g.mode[z];
  const int tid = threadIdx.x;
  const int wid = tid >> 6, lane = tid & 63;
  const int wr = wid >> 1, wc = wid & 1;
  const int lo = lane & 15, hi = lane >> 4;
  const int rs = tid >> 3, us = tid & 7;
  const int sw = (us ^ (rs & 7)) * 8;   // pre-swizzled source column unit

  f32x4 acc[4][4];
  const f32x4 z4 = {0.f, 0.f, 0.f, 0.f};
  #pragma unroll
  for (int i = 0; i < 4; ++i)
    #pragma unroll
    for (int j = 0; j < 4; ++j) acc[i][j] = z4;

  for (int kt = 0; kt < K / 64; ++kt) {
    __syncthreads();
    #pragma unroll
    for (int c = 0; c < 4; ++c) {
      int r = c * 32 + rs;
      GLOAD_LDS16(Ap + (size_t)(row0 + r) * K + kt * 64 + sw, &As[r * 64 + us * 8]);
      GLOAD_LDS16(Bt + (size_t)(col0 + r) * K + kt * 64 + sw, &Bs[r * 64 + us * 8]);
    }
    __syncthreads();   // compiler drains vmcnt before s_barrier
    #pragma unroll
    for (int ks = 0; ks < 2; ++ks) {
      bf16x8 af[4], bfr[4];
      #pragma unroll
      for (int mf = 0; mf < 4; ++mf) {
        int r = wr * 64 + mf * 16 + lo;
        af[mf] = *(const bf16x8*)&As[r * 64 + (((ks * 4 + hi) ^ (r & 7)) << 3)];
      }
      #pragma unroll
      for (int nf = 0; nf < 4; ++nf) {
        int r = wc * 64 + nf * 16 + lo;
        bfr[nf] = *(const bf16x8*)&Bs[r * 64 + (((ks * 4 + hi) ^ (r & 7)) << 3)];
      }
      #pragma unroll
      for (int mf = 0; mf < 4; ++mf)
        #pragma unroll
        for (int nf = 0; nf < 4; ++nf)
          acc[mf][nf] = __builtin_amdgcn_mfma_f32_16x16x32_bf16(af[mf], bfr[nf], acc[mf][nf], 0, 0, 0);
    }
  }

  #pragma unroll
  for (int nf = 0; nf < 4; ++nf) {
    int col = col0 + wc * 64 + nf * 16 + lo;
    float bv = bias[col];
    #pragma unroll
    for (int mf = 0; mf < 4; ++mf) {
      int rb = row0 + wr * 64 + mf * 16 + hi * 4;   // C/D: row=(l>>4)*4+e, col=l&15
      if (mode == 2) {
        U16Q q4;
        #pragma unroll
        for (int e = 0; e < 4; ++e) q4.u[e] = f2b(acc[mf][nf][e] + bv);
        *(uint2*)&((u16*)g.C[z])[(size_t)col * 4096 + rb] = q4.d2;   // C^T[N][4096]
      } else {
        #pragma unroll
        for (int e = 0; e < 4; ++e) {
          float v = acc[mf][nf][e] + bv;
          if (mode == 1) ((float*)g.C[z])[(size_t)(rb + e) * N + col] = v;
          else           ((u16*)g.C[z])[(size_t)(rb + e) * N + col] = f2b(v);
        }
      }
    }
  }
}

// ---------------- flash attention ----------------
// R7 compute body (validated 79.9us, VGPR=56, WRITE=8MB) with the staging
// restructured to catalog T3 "minimum 2-phase": double-buffered K/V staged by
// global_load_lds (zero registers held across barriers -> no R4/R5 spill
// hazard), ONE barrier per k-iter. Order per iter: barrier (drains vmcnt ->
// buf[cur] ready, prev readers of buf[cur^1] done) -> issue STAGE(kb+1 ->
// buf[cur^1]) -> compute(buf[cur]). Loads hide under QK+softmax+PV.
// Dest linear per wave (r*128 + lane*16 bytes); source pre-swizzled us^(r&7).
__global__ __launch_bounds__(256) void attn_fwd(const u16* __restrict__ Q,
                                                const u16* __restrict__ Kp,
                                                const u16* __restrict__ VpT,
                                                u16* __restrict__ O) {
  __shared__ u16 Ks[2][64 * 64];    // K tiles [kk][d], XOR-swizzled rows
  __shared__ u16 Vts[2][64 * 64];   // V^T tiles [d][kk], XOR-swizzled rows
  __shared__ u16 Ps[64 * 64];       // P tile [q][kk], per-wave rows
  const int tid = threadIdx.x;
  // XCD-aware decode: xcd = bid&7 owns 4 (h,b) pairs -> K/V L2-resident
  const int bid = blockIdx.x;
  const int t = bid >> 3;
  const int hb = (bid & 7) * 4 + (t >> 5);
  const int qb = t & 31;
  const int h = hb & 15, b = hb >> 4;
  const int wid = tid >> 6, lane = tid & 63;
  const int lo = lane & 15, hi = lane >> 4;
  const int rs = tid >> 3, us = tid & 7;
  const int hoff = h * 64;
  const size_t rowQ0 = (size_t)b * 2048 + (size_t)qb * 64;
  const float QSCALE = 0.125f * 1.4426950408889634f;

  // Q fragments (B-operand): lane holds Q[q = wid*16+lo][d = ks*32 + hi*8 .. +8]
  bf16x8 qf[2];
  #pragma unroll
  for (int ks = 0; ks < 2; ++ks) {
    size_t r = rowQ0 + wid * 16 + lo;
    U16B in; in.i4 = *(const int4*)&Q[r * 1024 + hoff + ks * 32 + hi * 8];
    U16B o;
    #pragma unroll
    for (int j = 0; j < 8; ++j) o.u[j] = f2b(b2f(in.u[j]) * QSCALE);
    qf[ks] = o.b8;
  }

  f32x4 oacc[4];
  const f32x4 z4 = {0.f, 0.f, 0.f, 0.f};
  #pragma unroll
  for (int df = 0; df < 4; ++df) oacc[df] = z4;
  float m_r = -1e30f, l_r = 0.f;   // row stats for q = wid*16+lo (replicated over hi)

  // prologue: stage tile 0 into buffer 0
  #pragma unroll
  for (int c = 0; c < 2; ++c) {
    int r = c * 32 + rs;
    int swu = (us ^ (r & 7)) * 8;
    GLOAD_LDS16(&Kp[((size_t)b * 2048 + r) * 1024 + hoff + swu], &Ks[0][r * 64 + us * 8]);
    GLOAD_LDS16(&VpT[(size_t)(hoff + r) * 4096 + b * 2048 + swu], &Vts[0][r * 64 + us * 8]);
  }

  for (int kb = 0; kb < 32; ++kb) {
    const int cur = kb & 1;
    __syncthreads();   // vmcnt drained: buf[cur] ready; buf[cur^1] readers done
    if (kb < 31) {
      const int kv0 = (kb + 1) * 64;
      #pragma unroll
      for (int c = 0; c < 2; ++c) {
        int r = c * 32 + rs;
        int swu = (us ^ (r & 7)) * 8;
        GLOAD_LDS16(&Kp[((size_t)b * 2048 + kv0 + r) * 1024 + hoff + swu],
                    &Ks[cur ^ 1][r * 64 + us * 8]);
        GLOAD_LDS16(&VpT[(size_t)(hoff + r) * 4096 + b * 2048 + kv0 + swu],
                    &Vts[cur ^ 1][r * 64 + us * 8]);
      }
    }

    // S^T = K Q^T : frag nf covers kk = nf*16 + hi*4 + e, q = wid*16+lo
    f32x4 sfr[4];
    #pragma unroll
    for (int nf = 0; nf < 4; ++nf) sfr[nf] = z4;
    #pragma unroll
    for (int ks = 0; ks < 2; ++ks) {
      #pragma unroll
      for (int nf = 0; nf < 4; ++nf) {
        int kk = nf * 16 + lo;
        bf16x8 kf = *(const bf16x8*)&Ks[cur][kk * 64 + (((ks * 4 + hi) ^ (kk & 7)) << 3)];
        sfr[nf] = __builtin_amdgcn_mfma_f32_16x16x32_bf16(kf, qf[ks], sfr[nf], 0, 0, 0);
      }
    }

    // online softmax (16 values per lane, reduce over hi via 2 shfl)
    float pm = -1e30f;
    #pragma unroll
    for (int nf = 0; nf < 4; ++nf)
      #pragma unroll
      for (int e = 0; e < 4; ++e) pm = fmaxf(pm, sfr[nf][e]);
    pm = fmaxf(pm, __shfl_xor(pm, 16));
    pm = fmaxf(pm, __shfl_xor(pm, 32));
    float mn = fmaxf(m_r, pm);
    float cc = __builtin_amdgcn_exp2f(m_r - mn);
    m_r = mn;
    float ps = 0.f;
    #pragma unroll
    for (int nf = 0; nf < 4; ++nf) {
      PK4 pk;
      #pragma unroll
      for (int e = 0; e < 4; ++e) {
        float p = __builtin_amdgcn_exp2f(sfr[nf][e] - mn);
        ps += p;
        pk.b[e] = (__bf16)p;     // native cast -> packed cvt
      }
      *(uint2*)&Ps[(wid * 16 + lo) * 64 + ((nf * 16 + hi * 4) ^ ((lo & 7) << 3))] = pk.d2;
    }
    ps += __shfl_xor(ps, 16);
    ps += __shfl_xor(ps, 32);
    l_r = l_r * cc + ps;
    float cce[4];
    #pragma unroll
    for (int e = 0; e < 4; ++e) cce[e] = __shfl(cc, hi * 4 + e);

    // O = O*cc + P V   (Ps rows are per-wave exclusive: no block barrier)
    #pragma unroll
    for (int ksp = 0; ksp < 2; ++ksp) {
      bf16x8 pa = *(const bf16x8*)&Ps[(wid * 16 + lo) * 64 + ((((ksp * 4 + hi) ^ (lo & 7))) << 3)];
      bf16x8 vb[4];
      #pragma unroll
      for (int df = 0; df < 4; ++df) {
        int d = df * 16 + lo;
        vb[df] = *(const bf16x8*)&Vts[cur][d * 64 + (((ksp * 4 + hi) ^ (d & 7)) << 3)];
      }
      if (ksp == 0) {
        #pragma unroll
        for (int df = 0; df < 4; ++df)
          #pragma unroll
          for (int e = 0; e < 4; ++e) oacc[df][e] *= cce[e];
      }
      #pragma unroll
      for (int df = 0; df < 4; ++df)
        oacc[df] = __builtin_amdgcn_mfma_f32_16x16x32_bf16(pa, vb[df], oacc[df], 0, 0, 0);
    }
  }

  // epilogue: normalize (stats live at q=wid*16+lo; O rows are q=hi*4+e -> gather)
  float inv = __builtin_amdgcn_rcpf(l_r);
  float inve[4];
  #pragma unroll
  for (int e = 0; e < 4; ++e) inve[e] = __shfl(inv, hi * 4 + e);
  #pragma unroll
  for (int df = 0; df < 4; ++df)
    #pragma unroll
    for (int e = 0; e < 4; ++e) {
      size_t row = rowQ0 + wid * 16 + hi * 4 + e;
      O[row * 1024 + hoff + df * 16 + lo] = f2b(oacc[df][e] * inve[e]);
    }
}

// ---------------- launch ----------------
extern "C" void kernel_launch(void* const* d_in, const int* in_sizes, int n_in,
                              void* d_out, int out_size, void* d_ws, size_t ws_size,
                              hipStream_t stream) {
  (void)in_sizes; (void)n_in; (void)out_size;
  const size_t MB = 1024 * 1024;
  if (ws_size < 40 * MB) return;
  char* ws = (char*)d_ws;
  u16* Wqt = (u16*)(ws + 0 * MB);
  u16* Wkt = (u16*)(ws + 2 * MB);
  u16* Wvt = (u16*)(ws + 4 * MB);
  u16* Wot = (u16*)(ws + 6 * MB);
  u16* Vb  = (u16*)(ws + 8 * MB);    // bf16 value-input; later reused as Op
  u16* Qp  = (u16*)(ws + 16 * MB);
  u16* Kp  = (u16*)(ws + 24 * MB);
  u16* VpT = (u16*)(ws + 32 * MB);   // V^T [1024][4096]
  u16* Op  = (u16*)(ws + 8 * MB);    // reuse Vb space (dead after QKV GEMM)
  // bf16 query/key inputs parked in d_out (16MB; overwritten by final GEMM)
  u16* Qb = (u16*)d_out;
  u16* Kb = (u16*)d_out + (size_t)4 * MB;   // element offset: 8MB bytes

  ConvA ca;
  ca.src[0] = (const float*)d_in[0]; ca.dst[0] = Qb;
  ca.src[1] = (const float*)d_in[1]; ca.dst[1] = Kb;
  ca.src[2] = (const float*)d_in[2]; ca.dst[2] = Vb;
  hipLaunchKernelGGL(convA, dim3(2048, 1, 3), dim3(256), 0, stream, ca);

  TransA ta;
  ta.W[0] = (const float*)d_in[3]; ta.Wt[0] = Wqt;
  ta.W[1] = (const float*)d_in[5]; ta.Wt[1] = Wkt;
  ta.W[2] = (const float*)d_in[7]; ta.Wt[2] = Wvt;
  ta.W[3] = (const float*)d_in[9]; ta.Wt[3] = Wot;
  hipLaunchKernelGGL(transW, dim3(16, 16, 4), dim3(256), 0, stream, ta);

  GemmB gp;
  gp.A[0] = Qb; gp.Bt[0] = Wqt; gp.bias[0] = (const float*)d_in[4]; gp.C[0] = Qp;  gp.mode[0] = 0;
  gp.A[1] = Kb; gp.Bt[1] = Wkt; gp.bias[1] = (const float*)d_in[6]; gp.C[1] = Kp;  gp.mode[1] = 0;
  gp.A[2] = Vb; gp.Bt[2] = Wvt; gp.bias[2] = (const float*)d_in[8]; gp.C[2] = VpT; gp.mode[2] = 2;
  gp.cpx = 96;
  hipLaunchKernelGGL(gemm_bt, dim3(768), dim3(256), 0, stream, gp);

  hipLaunchKernelGGL(attn_fwd, dim3(1024), dim3(256), 0, stream, Qp, Kp, VpT, Op);

  GemmB gf;
  gf.A[0] = Op; gf.Bt[0] = Wot; gf.bias[0] = (const float*)d_in[10]; gf.C[0] = (void*)d_out; gf.mode[0] = 1;
  gf.A[1] = nullptr; gf.A[2] = nullptr; gf.Bt[1] = nullptr; gf.Bt[2] = nullptr;
  gf.bias[1] = nullptr; gf.bias[2] = nullptr; gf.C[1] = nullptr; gf.C[2] = nullptr;
  gf.mode[1] = 0; gf.mode[2] = 0;
  gf.cpx = 32;
  hipLaunchKernelGGL(gemm_bt, dim3(256), dim3(256), 0, stream, gf);
}